// Round 8
// baseline (517.824 us; speedup 1.0000x reference)
//
#include <hip/hip_runtime.h>
#include <math.h>

#define NN 100000
#define EE 1600000
#define GG 512
#define INF_ 128
#define HID 64
#define EPS 1e-5f

#define NBUK 391          // ceil(NN/256), bucket = dst >> 8
#define P1_TILES 98       // ceil((EE/4)/4096)
#define P1_PAD 104        // hblk row stride (98 padded to 8n for int4 loads)
#define GB_B 25           // graph-boundary role blocks
#define GEMM1_B 1563      // ceil(NN/64)

typedef unsigned int uint32;
typedef __attribute__((ext_vector_type(8))) short bf16x8;
typedef __attribute__((ext_vector_type(4))) float f32x4;
typedef __attribute__((ext_vector_type(2))) float f32x2;

// bf16 helpers: RNE pack, shift decode
static __device__ inline uint32 f2bf(float f) {
    uint32 u = __float_as_uint(f);
    return (u + 0x7FFFu + ((u >> 16) & 1u)) >> 16;
}
static __device__ inline float bf_lo(uint32 u) { return __uint_as_float(u << 16); }
static __device__ inline float bf_hi(uint32 u) { return __uint_as_float(u & 0xFFFF0000u); }

// History:
// R3: per-edge atomic scatter -> 12x cross-XCD write amp; bucketed 2-level sort.
// R9: single-histogram CSR build; 303us baseline.
// R10 FAILED: per-thread s[16] -> PromoteAlloca -> 64KB LDS, 38M bank conf.
// R11: gather memory-bound; instruction shaving (-30% VALU) bought only 5%.
// R12: launch fusion 10->8; 297.7. Gather at compulsory per-XCD L2-fill floor.
// R13: hwb fp8-e4m3 (table 6.4MB ~ L2-resident); 285.9. absmax 0 -> fp8 ok.
// R14 REGRESSED (299.8): 98-iter scalar-load loop in p1b (serialized latency).
// R15 (284.8): transposed hblk + int4 unrolled derivation fixed p1b.
// R16 (271.9): 2-node/wave interleaved gathers + bf16 h1. Gathers ~30us each,
//      still 4-5x issue floor: wave-per-node serializes col->row chains.
// R17: EDGE-PARALLEL gather. Block = bucket (256 nodes), acc[256][64] f32 in
//      LDS (64KB exactly - R10 proved it compiles). Edges are dst-sorted
//      within bucket (p2), so 16 slots/block stream contiguous sub-ranges
//      with REGISTER per-segment accumulation; LDS atomicAdd only at segment
//      boundaries (~1/16 edges). Depth-2 SW pipeline (addresses independent
//      of data - not R14's trap). offs[] deleted pipeline-wide; p2 stores
//      packed (src<<8)|dloc (= u itself). mega/p1b/gemm2/poolhead unchanged.

// ---------------- shared GEMM body: [nrows,K]f32 @ W[K,64]f32 -> fp8 ------
template <int K, bool SCALE>
__device__ __forceinline__ void gemm_body(const float* __restrict__ X,
        const float* __restrict__ W, const float* __restrict__ dinv,
        uint32* __restrict__ outb, int nrows, int bx,
        unsigned short* __restrict__ Al, unsigned short* __restrict__ Bl) {
    constexpr int KP = K + 8;
    int tid = threadIdx.x;
    // pack W transposed: Bl[n*KP + 2kp] = pack(W[2kp][n], W[2kp+1][n]).
    for (int i = tid; i < 64 * (K / 2); i += 256) {
        int n = i & 63, kp = i >> 6;
        uint32 lo = f2bf(W[(size_t)(2 * kp) * 64 + n]);
        uint32 hi = f2bf(W[(size_t)(2 * kp + 1) * 64 + n]);
        *(uint32*)&Bl[n * KP + kp * 2] = lo | (hi << 16);
    }
    int r0 = bx * 64;
    const float* Xb = X + (size_t)r0 * K;
    int limit = (nrows - r0) * K;
    for (int f = tid * 4; f < 64 * K; f += 1024) {
        float4 v = {0.f, 0.f, 0.f, 0.f};
        if (f + 3 < limit) v = *(const float4*)&Xb[f];
        int row = f / K, kpos = f % K;
        ushort4 pk;
        pk.x = (unsigned short)f2bf(v.x);
        pk.y = (unsigned short)f2bf(v.y);
        pk.z = (unsigned short)f2bf(v.z);
        pk.w = (unsigned short)f2bf(v.w);
        *(ushort4*)&Al[row * KP + kpos] = pk;
    }
    __syncthreads();
    int lane = tid & 63, wv = tid >> 6;
    int m = lane & 15, quad = lane >> 4;
    f32x4 acc0 = {0.f, 0.f, 0.f, 0.f}, acc1 = acc0, acc2 = acc0, acc3 = acc0;
    int arow = wv * 16 + m;
#pragma unroll
    for (int k0 = 0; k0 < K; k0 += 32) {
        int koff = k0 + quad * 8;
        bf16x8 a = *(const bf16x8*)&Al[arow * KP + koff];
        bf16x8 b0 = *(const bf16x8*)&Bl[(0 * 16 + m) * KP + koff];
        bf16x8 b1 = *(const bf16x8*)&Bl[(1 * 16 + m) * KP + koff];
        bf16x8 b2 = *(const bf16x8*)&Bl[(2 * 16 + m) * KP + koff];
        bf16x8 b3 = *(const bf16x8*)&Bl[(3 * 16 + m) * KP + koff];
        acc0 = __builtin_amdgcn_mfma_f32_16x16x32_bf16(a, b0, acc0, 0, 0, 0);
        acc1 = __builtin_amdgcn_mfma_f32_16x16x32_bf16(a, b1, acc1, 0, 0, 0);
        acc2 = __builtin_amdgcn_mfma_f32_16x16x32_bf16(a, b2, acc2, 0, 0, 0);
        acc3 = __builtin_amdgcn_mfma_f32_16x16x32_bf16(a, b3, acc3, 0, 0, 0);
    }
    // C/D layout: col = nt*16 + m, row = quad*4 + reg.
    float dv[4];
#pragma unroll
    for (int reg = 0; reg < 4; ++reg) {
        int row = r0 + wv * 16 + quad * 4 + reg;
        if (SCALE) dv[reg] = (row < nrows) ? dinv[row] : 0.f;
        else       dv[reg] = 1.f;
    }
    const float* accs[4] = {(const float*)&acc0, (const float*)&acc1,
                            (const float*)&acc2, (const float*)&acc3};
#pragma unroll
    for (int nt = 0; nt < 4; ++nt) {
#pragma unroll
        for (int reg = 0; reg < 4; ++reg) {
            float val = accs[nt][reg] * dv[reg];
            float v1 = __shfl_down(val, 1);
            float v2 = __shfl_down(val, 2);
            float v3 = __shfl_down(val, 3);
            int row = r0 + wv * 16 + quad * 4 + reg;
            if (((m & 3) == 0) && row < nrows) {
                int u = __builtin_amdgcn_cvt_pk_fp8_f32(val, v1, 0, false);
                u = __builtin_amdgcn_cvt_pk_fp8_f32(v2, v3, u, true);
                outb[(size_t)row * 16 + nt * 4 + (m >> 2)] = (uint32)u;
            }
        }
    }
}

// ------- mega front-end: hist | graph-bounds | setup | gemm1 (unscaled) ----
__global__ __launch_bounds__(256) void k_mega(const int* __restrict__ ei,
        int* __restrict__ hblk, const int* __restrict__ bat, int* __restrict__ gb,
        const float* __restrict__ x, const float* __restrict__ W1,
        uint32* __restrict__ hwb,
        const float* b1, const float* g1, const float* be1,
        const float* rm1, const float* rv1,
        const float* b2, const float* g2, const float* be2,
        const float* rm2, const float* rv2, float* sc) {
    __shared__ alignas(16) char smem[64 * (INF_ + 8) * 2 * 2];
    int b = blockIdx.x, t = threadIdx.x;
    if (b < P1_TILES) {
        int* h = (int*)smem;
        for (int i = t; i < NBUK; i += 256) h[i] = 0;
        __syncthreads();
        const int4* dst4 = (const int4*)(ei + EE);
        int base4 = b * 4096;
        for (int j = 0; j < 16; ++j) {
            int i4 = base4 + j * 256 + t;
            if (i4 < EE / 4) {
                int4 d = dst4[i4];
                atomicAdd(&h[d.x >> 8], 1);
                atomicAdd(&h[d.y >> 8], 1);
                atomicAdd(&h[d.z >> 8], 1);
                atomicAdd(&h[d.w >> 8], 1);
            }
        }
        __syncthreads();
        for (int i = t; i < NBUK; i += 256) hblk[i * P1_PAD + b] = h[i];
    } else if (b < P1_TILES + GB_B) {
        // gb[g] = first node index with batch >= g (batch sorted). gb[GG]=NN.
        int gid = (b - P1_TILES) * 256 + t;
        for (int i = gid; i < NN; i += GB_B * 256) {
            int bi = bat[i];
            if (i == 0) {
                for (int g = 0; g <= bi; ++g) gb[g] = 0;
            } else {
                int bp = bat[i - 1];
                for (int g = bp + 1; g <= bi; ++g) gb[g] = i;
            }
            if (i == NN - 1)
                for (int g = bi + 1; g <= GG; ++g) gb[g] = NN;
        }
    } else if (b < P1_TILES + GB_B + 1) {
        // setup role: BN fold (t<64), hwb zero row (64..79), hblk pad zero
        if (t < 64) {
            int l = t;
            float s1 = g1[l] * rsqrtf(rv1[l] + EPS);
            sc[l]       = s1;
            sc[64 + l]  = (b1[l] - rm1[l]) * s1 + be1[l];
            float s2 = g2[l] * rsqrtf(rv2[l] + EPS);
            sc[128 + l] = s2;
            sc[192 + l] = (b2[l] - rm2[l]) * s2 + be2[l];
        } else if (t < 80) {
            hwb[(size_t)NN * 16 + (t - 64)] = 0u;
        }
        // pads [98..104) of every hblk row (re-poisoned each run)
        for (int i = t; i < NBUK * (P1_PAD - P1_TILES); i += 256) {
            int k = i / (P1_PAD - P1_TILES);
            int bb = P1_TILES + i % (P1_PAD - P1_TILES);
            hblk[k * P1_PAD + bb] = 0;
        }
    } else {
        int bx = b - P1_TILES - GB_B - 1;
        unsigned short* Al = (unsigned short*)smem;
        unsigned short* Bl = (unsigned short*)(smem + 64 * (INF_ + 8) * 2);
        gemm_body<INF_, false>(x, W1, nullptr, hwb, NN, bx, Al, Bl);
    }
}

// -------- p1b: per-block rbase derivation + bucket scatter, 512 thr -------
__global__ __launch_bounds__(512) void k_p1b(const int* __restrict__ ei,
                                             const int* __restrict__ hblk,
                                             uint32* __restrict__ pairs,
                                             int* __restrict__ bbase) {
    __shared__ int h[NBUK];
    __shared__ int wsum[8];
    int b = blockIdx.x, t = threadIdx.x;
    int part = 0, c = 0;
    if (t < NBUK) {
        const int4* row = (const int4*)(hblk + t * P1_PAD);
#pragma unroll
        for (int q = 0; q < P1_PAD / 4; ++q) {
            int4 v = row[q];
            c += v.x + v.y + v.z + v.w;
            part += ((4 * q + 0 < b) ? v.x : 0) + ((4 * q + 1 < b) ? v.y : 0)
                  + ((4 * q + 2 < b) ? v.z : 0) + ((4 * q + 3 < b) ? v.w : 0);
        }
    }
    int lane = t & 63, w = t >> 6;
    int v = c;
    for (int d = 1; d < 64; d <<= 1) { int n = __shfl_up(v, d); if (lane >= d) v += n; }
    if (lane == 63) wsum[w] = v;
    __syncthreads();
    int pre = 0;
    for (int q = 0; q < w; ++q) pre += wsum[q];
    int excl = pre + v - c;
    if (t < NBUK) h[t] = excl + part;
    if (b == 0 && t <= NBUK) bbase[t] = excl;   // t=391 -> EE
    __syncthreads();
    const int4* src4 = (const int4*)ei;
    const int4* dst4 = (const int4*)(ei + EE);
    int base4 = b * 4096;
    for (int j = 0; j < 8; ++j) {
        int i4 = base4 + j * 512 + t;
        if (i4 < EE / 4) {
            int4 d = dst4[i4];
            int4 s = src4[i4];
            int p0 = atomicAdd(&h[d.x >> 8], 1);
            pairs[p0] = ((uint32)s.x << 8) | (uint32)(d.x & 255);
            int p1 = atomicAdd(&h[d.y >> 8], 1);
            pairs[p1] = ((uint32)s.y << 8) | (uint32)(d.y & 255);
            int p2 = atomicAdd(&h[d.z >> 8], 1);
            pairs[p2] = ((uint32)s.z << 8) | (uint32)(d.z & 255);
            int p3 = atomicAdd(&h[d.w >> 8], 1);
            pairs[p3] = ((uint32)s.w << 8) | (uint32)(d.w & 255);
        }
    }
}

// per-bucket (256 nodes) CSR finalize in LDS: count -> dinv; scan; scatter
// PACKED entries (src<<8)|dloc = u itself (R17: gather needs dloc too).
__global__ __launch_bounds__(256) void k_p2(const uint32* __restrict__ pairs,
                                            const int* __restrict__ bbase,
                                            float* __restrict__ dinv,
                                            uint32* __restrict__ col) {
    int b = blockIdx.x, t = threadIdx.x;
    int nbase = b << 8;
    int ebase = bbase[b], eend = bbase[b + 1];
    int m = eend - ebase;
    __shared__ int cnt[256];
    __shared__ int wsum[4];
    cnt[t] = 0;
    __syncthreads();
    for (int i = t; i < m; i += 256)
        atomicAdd(&cnt[pairs[ebase + i] & 255u], 1);
    __syncthreads();
    int c = cnt[t];
    int lane = t & 63, w = t >> 6;
    int v = c;
    for (int d = 1; d < 64; d <<= 1) { int n = __shfl_up(v, d); if (lane >= d) v += n; }
    if (lane == 63) wsum[w] = v;
    __syncthreads();
    int pre = 0;
    for (int q = 0; q < w; ++q) pre += wsum[q];
    int excl = pre + v - c;
    int node = nbase + t;
    if (node < NN) dinv[node] = rsqrtf(1.f + (float)c);
    __syncthreads();
    cnt[t] = excl;
    __syncthreads();
    for (int i = t; i < m; i += 256) {
        uint32 u = pairs[ebase + i];
        int loc = atomicAdd(&cnt[u & 255u], 1);
        col[ebase + loc] = u;           // packed (src<<8)|dloc, dst-sorted
    }
}

// -------- R17 edge-parallel gather: block = bucket, acc[256][64] in LDS ----
// 16 slots (4 waves x 4 quarters) stream contiguous dst-sorted edge ranges;
// 16 lanes/slot cover a 64B fp8 row (4 feats/lane). Register accumulation
// per node segment; LDS atomicAdd only at segment boundaries (~1/16 edges).
// Depth-2 SW pipeline (e+1 addresses data-independent). Epilogue: verified
// R16 per-node math. WEIGHTED=layer1 (dinv[src] weight, bf16 out);
// else layer2 (pre-scaled rows, bf16 resid, f32 out).
template <bool WEIGHTED>
__global__ __launch_bounds__(256) void k_gather_ep(
        const uint32* __restrict__ hwb, const uint32* __restrict__ colp,
        const int* __restrict__ bbase, const float* __restrict__ dinv,
        const float* __restrict__ scale, const float* __restrict__ shift,
        const uint32* __restrict__ resid, uint32* __restrict__ outb16,
        float* __restrict__ outf32) {
    __shared__ float acc[256 * 64];      // 64KB exactly (2 blocks/CU)
    int t = threadIdx.x, b = blockIdx.x;
    float4 z4 = {0.f, 0.f, 0.f, 0.f};
    for (int i = t * 4; i < 256 * 64; i += 1024) *(float4*)&acc[i] = z4;
    __syncthreads();
    int e0 = bbase[b], e1 = bbase[b + 1];
    int m = e1 - e0;
    int lane = t & 63, quarter = lane >> 4, fl = lane & 15, wv = t >> 6;
    int slot = wv * 4 + quarter;
    int len = (m + 15) >> 4;
    int sbeg = e0 + slot * len;
    int send = sbeg + len; if (send > e1) send = e1;
    int cur = -1;
    float a0 = 0.f, a1 = 0.f, a2 = 0.f, a3 = 0.f;
    if (sbeg < send) {
        uint32 u = colp[sbeg];
        uint32 row = hwb[(size_t)(u >> 8) * 16 + fl];
        float w = WEIGHTED ? dinv[u >> 8] : 0.f;
        for (int e = sbeg; e < send; ++e) {
            int e2 = (e + 1 < send) ? (e + 1) : e;   // clamped prefetch
            uint32 un = colp[e2];
            uint32 rown = hwb[(size_t)(un >> 8) * 16 + fl];
            float wn = WEIGHTED ? dinv[un >> 8] : 0.f;
            int nl = (int)(u & 255u);
            if (nl != cur) {                          // quarter-uniform branch
                if (cur >= 0) {
                    atomicAdd(&acc[cur * 64 + 4 * fl + 0], a0);
                    atomicAdd(&acc[cur * 64 + 4 * fl + 1], a1);
                    atomicAdd(&acc[cur * 64 + 4 * fl + 2], a2);
                    atomicAdd(&acc[cur * 64 + 4 * fl + 3], a3);
                }
                cur = nl; a0 = a1 = a2 = a3 = 0.f;
            }
            f32x2 lo = __builtin_amdgcn_cvt_pk_f32_fp8((int)row, false);
            f32x2 hi = __builtin_amdgcn_cvt_pk_f32_fp8((int)row, true);
            if (WEIGHTED) {
                a0 = fmaf(lo[0], w, a0); a1 = fmaf(lo[1], w, a1);
                a2 = fmaf(hi[0], w, a2); a3 = fmaf(hi[1], w, a3);
            } else {
                a0 += lo[0]; a1 += lo[1]; a2 += hi[0]; a3 += hi[1];
            }
            u = un; row = rown; w = wn;
        }
        if (cur >= 0) {
            atomicAdd(&acc[cur * 64 + 4 * fl + 0], a0);
            atomicAdd(&acc[cur * 64 + 4 * fl + 1], a1);
            atomicAdd(&acc[cur * 64 + 4 * fl + 2], a2);
            atomicAdd(&acc[cur * 64 + 4 * fl + 3], a3);
        }
    }
    __syncthreads();
    // epilogue: quarter q handles node r*16 + wv*4 + q, lanes = 4 feats each
    int nbase = b << 8;
    for (int r = 0; r < 16; ++r) {
        int nl = r * 16 + wv * 4 + quarter;
        int node = nbase + nl;
        if (node >= NN) continue;
        float4 s4 = *(float4*)&acc[nl * 64 + 4 * fl];
        float di = dinv[node];
        uint32 uself = hwb[(size_t)node * 16 + fl];
        f32x2 slo = __builtin_amdgcn_cvt_pk_f32_fp8((int)uself, false);
        f32x2 shi = __builtin_amdgcn_cvt_pk_f32_fp8((int)uself, true);
        float4 sc4 = *(const float4*)&scale[4 * fl];
        float4 sh4 = *(const float4*)&shift[4 * fl];
        if (WEIGHTED) {
            float dii = di * di;
            float v0 = fmaf(s4.x * di + slo[0] * dii, sc4.x, sh4.x);
            float v1 = fmaf(s4.y * di + slo[1] * dii, sc4.y, sh4.y);
            float v2 = fmaf(s4.z * di + shi[0] * dii, sc4.z, sh4.z);
            float v3 = fmaf(s4.w * di + shi[1] * dii, sc4.w, sh4.w);
            v0 = fmaxf(v0, 0.f); v1 = fmaxf(v1, 0.f);
            v2 = fmaxf(v2, 0.f); v3 = fmaxf(v3, 0.f);
            uint2 o;
            o.x = f2bf(v0) | (f2bf(v1) << 16);
            o.y = f2bf(v2) | (f2bf(v3) << 16);
            *(uint2*)&outb16[(size_t)node * 32 + 2 * fl] = o;
        } else {
            float v0 = fmaf((s4.x + slo[0]) * di, sc4.x, sh4.x);
            float v1 = fmaf((s4.y + slo[1]) * di, sc4.y, sh4.y);
            float v2 = fmaf((s4.z + shi[0]) * di, sc4.z, sh4.z);
            float v3 = fmaf((s4.w + shi[1]) * di, sc4.w, sh4.w);
            uint2 rv = *(const uint2*)&resid[(size_t)node * 32 + 2 * fl];
            float4 o;
            o.x = fmaxf(v0, 0.f) + bf_lo(rv.x);
            o.y = fmaxf(v1, 0.f) + bf_hi(rv.x);
            o.z = fmaxf(v2, 0.f) + bf_lo(rv.y);
            o.w = fmaxf(v3, 0.f) + bf_hi(rv.y);
            *(float4*)&outf32[(size_t)node * 64 + 4 * fl] = o;
        }
    }
}

// ---------------- fused pooling + MLP head: one block per graph -----------
__global__ void k_poolhead(const float* __restrict__ h, const int* __restrict__ gb,
                           const float* __restrict__ Wh1, const float* __restrict__ bh1,
                           const float* __restrict__ Wh2, const float* __restrict__ bh2,
                           const float* __restrict__ Wh3, const float* __restrict__ bh3,
                           float* __restrict__ out) {
    int g = blockIdx.x, t = threadIdx.x;  // 64 threads
    int lo = gb[g], hi = gb[g + 1];
    float s0 = 0.f, s1 = 0.f, s2 = 0.f, s3 = 0.f;
    float s4 = 0.f, s5 = 0.f, s6 = 0.f, s7 = 0.f;
    float m0 = 0.f, m1 = 0.f, m2 = 0.f, m3 = 0.f;
    float m4 = 0.f, m5 = 0.f, m6 = 0.f, m7 = 0.f;   // h >= 0 (post-ReLU chain)
    int i = lo;
    for (; i + 8 <= hi; i += 8) {
        float v0 = h[(size_t)(i + 0) * 64 + t];
        float v1 = h[(size_t)(i + 1) * 64 + t];
        float v2 = h[(size_t)(i + 2) * 64 + t];
        float v3 = h[(size_t)(i + 3) * 64 + t];
        float v4 = h[(size_t)(i + 4) * 64 + t];
        float v5 = h[(size_t)(i + 5) * 64 + t];
        float v6 = h[(size_t)(i + 6) * 64 + t];
        float v7 = h[(size_t)(i + 7) * 64 + t];
        s0 += v0; m0 = fmaxf(m0, v0);
        s1 += v1; m1 = fmaxf(m1, v1);
        s2 += v2; m2 = fmaxf(m2, v2);
        s3 += v3; m3 = fmaxf(m3, v3);
        s4 += v4; m4 = fmaxf(m4, v4);
        s5 += v5; m5 = fmaxf(m5, v5);
        s6 += v6; m6 = fmaxf(m6, v6);
        s7 += v7; m7 = fmaxf(m7, v7);
    }
    for (; i < hi; ++i) {
        float v = h[(size_t)i * 64 + t];
        s0 += v; m0 = fmaxf(m0, v);
    }
    float sum = ((s0 + s1) + (s2 + s3)) + ((s4 + s5) + (s6 + s7));
    float mx = fmaxf(fmaxf(fmaxf(m0, m1), fmaxf(m2, m3)),
                     fmaxf(fmaxf(m4, m5), fmaxf(m6, m7)));
    float c = fmaxf((float)(hi - lo), 1.f);
    __shared__ float hg[128];
    __shared__ float z1[64];
    __shared__ float z2[32];
    hg[t]      = sum / c;
    hg[64 + t] = mx;
    __syncthreads();
    float acc = bh1[t];
#pragma unroll 8
    for (int k = 0; k < 128; ++k) acc = fmaf(hg[k], Wh1[k * 64 + t], acc);
    z1[t] = fmaxf(acc, 0.f);
    __syncthreads();
    if (t < 32) {
        float a2 = bh2[t];
#pragma unroll 8
        for (int k = 0; k < 64; ++k) a2 = fmaf(z1[k], Wh2[k * 32 + t], a2);
        z2[t] = fmaxf(a2, 0.f);
    }
    __syncthreads();
    if (t == 0) {
        float a3 = bh3[0];
        for (int k = 0; k < 32; ++k) a3 = fmaf(z2[k], Wh3[k], a3);
        out[g] = 1.f / (1.f + expf(-a3));
    }
}

// ------- GEMM layer 2: bf16-packed input, dinv-scaled fp8 output ----------
__global__ __launch_bounds__(256) void k_gemm2(const uint32* __restrict__ Xb16,
                                               const float* __restrict__ W,
                                               const float* __restrict__ dinv,
                                               uint32* __restrict__ outb) {
    constexpr int K = HID, KP = K + 8;
    __shared__ alignas(16) unsigned short Al[64 * KP];
    __shared__ alignas(16) unsigned short Bl[64 * KP];
    int tid = threadIdx.x;
    for (int i = tid; i < 64 * (K / 2); i += 256) {
        int n = i & 63, kp = i >> 6;
        uint32 lo = f2bf(W[(size_t)(2 * kp) * 64 + n]);
        uint32 hi = f2bf(W[(size_t)(2 * kp + 1) * 64 + n]);
        *(uint32*)&Bl[n * KP + kp * 2] = lo | (hi << 16);
    }
    int r0 = blockIdx.x * 64;
    const uint32* Xr = Xb16 + (size_t)r0 * 32;
    int limit = (NN - r0) * 32;           // u32 units
    for (int f = tid * 4; f < 64 * 32; f += 1024) {
        uint4 v = {0u, 0u, 0u, 0u};
        if (f + 3 < limit) v = *(const uint4*)&Xr[f];
        int row = f >> 5, kpos = (f & 31) * 2;  // bf16 elements
        *(uint4*)&Al[row * KP + kpos] = v;
    }
    __syncthreads();
    int lane = tid & 63, wv = tid >> 6;
    int m = lane & 15, quad = lane >> 4;
    f32x4 acc0 = {0.f, 0.f, 0.f, 0.f}, acc1 = acc0, acc2 = acc0, acc3 = acc0;
    int arow = wv * 16 + m;
#pragma unroll
    for (int k0 = 0; k0 < K; k0 += 32) {
        int koff = k0 + quad * 8;
        bf16x8 a = *(const bf16x8*)&Al[arow * KP + koff];
        bf16x8 b0 = *(const bf16x8*)&Bl[(0 * 16 + m) * KP + koff];
        bf16x8 b1 = *(const bf16x8*)&Bl[(1 * 16 + m) * KP + koff];
        bf16x8 b2 = *(const bf16x8*)&Bl[(2 * 16 + m) * KP + koff];
        bf16x8 b3 = *(const bf16x8*)&Bl[(3 * 16 + m) * KP + koff];
        acc0 = __builtin_amdgcn_mfma_f32_16x16x32_bf16(a, b0, acc0, 0, 0, 0);
        acc1 = __builtin_amdgcn_mfma_f32_16x16x32_bf16(a, b1, acc1, 0, 0, 0);
        acc2 = __builtin_amdgcn_mfma_f32_16x16x32_bf16(a, b2, acc2, 0, 0, 0);
        acc3 = __builtin_amdgcn_mfma_f32_16x16x32_bf16(a, b3, acc3, 0, 0, 0);
    }
    float dv[4];
#pragma unroll
    for (int reg = 0; reg < 4; ++reg) {
        int row = r0 + wv * 16 + quad * 4 + reg;
        dv[reg] = (row < NN) ? dinv[row] : 0.f;
    }
    const float* accs[4] = {(const float*)&acc0, (const float*)&acc1,
                            (const float*)&acc2, (const float*)&acc3};
#pragma unroll
    for (int nt = 0; nt < 4; ++nt) {
#pragma unroll
        for (int reg = 0; reg < 4; ++reg) {
            float val = accs[nt][reg] * dv[reg];
            float v1 = __shfl_down(val, 1);
            float v2 = __shfl_down(val, 2);
            float v3 = __shfl_down(val, 3);
            int row = r0 + wv * 16 + quad * 4 + reg;
            if (((m & 3) == 0) && row < NN) {
                int u = __builtin_amdgcn_cvt_pk_fp8_f32(val, v1, 0, false);
                u = __builtin_amdgcn_cvt_pk_fp8_f32(v2, v3, u, true);
                outb[(size_t)row * 16 + nt * 4 + (m >> 2)] = (uint32)u;
            }
        }
    }
}

// ---------------- launcher ----------------

static inline size_t alignup(size_t x) { return (x + 255) & ~(size_t)255; }

extern "C" void kernel_launch(void* const* d_in, const int* in_sizes, int n_in,
                              void* d_out, int out_size, void* d_ws, size_t ws_size,
                              hipStream_t stream) {
    const float* x   = (const float*)d_in[0];
    const int*   ei  = (const int*)d_in[1];
    const int*   bat = (const int*)d_in[2];
    const float* W1  = (const float*)d_in[3];
    const float* b1  = (const float*)d_in[4];
    const float* g1  = (const float*)d_in[5];
    const float* be1 = (const float*)d_in[6];
    const float* rm1 = (const float*)d_in[7];
    const float* rv1 = (const float*)d_in[8];
    const float* W2  = (const float*)d_in[9];
    const float* b2  = (const float*)d_in[10];
    const float* g2  = (const float*)d_in[11];
    const float* be2 = (const float*)d_in[12];
    const float* rm2 = (const float*)d_in[13];
    const float* rv2 = (const float*)d_in[14];
    const float* Wh1 = (const float*)d_in[15];
    const float* bh1 = (const float*)d_in[16];
    const float* Wh2 = (const float*)d_in[17];
    const float* bh2 = (const float*)d_in[18];
    const float* Wh3 = (const float*)d_in[19];
    const float* bh3 = (const float*)d_in[20];
    float* out = (float*)d_out;

    char* ws = (char*)d_ws;
    size_t o = 0;
    int*   hblk   = (int*)(ws + o);  o = alignup(o + (size_t)NBUK * P1_PAD * 4);
    int*   bbase  = (int*)(ws + o);  o = alignup(o + (NBUK + 1) * 4);
    uint32* pairs = (uint32*)(ws + o); o = alignup(o + (size_t)EE * 4);
    uint32* col   = (uint32*)(ws + o); o = alignup(o + (size_t)EE * 4);
    float* dinv   = (float*)(ws + o); o = alignup(o + (size_t)NN * 4);
    float* scb    = (float*)(ws + o); o = alignup(o + 4 * 64 * 4);
    int*   gb     = (int*)(ws + o);  o = alignup(o + (GG + 1) * 4);
    uint32* hwb   = (uint32*)(ws + o); o = alignup(o + (size_t)(NN + 1) * 16 * 4); // fp8 rows, +1 zero row
    uint32* h1b   = (uint32*)(ws + o); o = alignup(o + (size_t)NN * 32 * 4);       // bf16-packed layer-1 out
    float* h      = (float*)(ws + o); o = alignup(o + (size_t)NN * 64 * 4);
    (void)ws_size; (void)n_in; (void)in_sizes; (void)out_size;

    // 1. front-end: hist(transposed) || graph-bounds || setup || gemm1
    k_mega<<<P1_TILES + GB_B + 1 + GEMM1_B, 256, 0, stream>>>(
        ei, hblk, bat, gb, x, W1, hwb,
        b1, g1, be1, rm1, rv1, b2, g2, be2, rm2, rv2, scb);
    // 2. bucket scatter (derives rbase from transposed hblk; publishes bbase)
    k_p1b<<<P1_TILES, 512, 0, stream>>>(ei, hblk, pairs, bbase);
    // 3. CSR finalize: dinv + dst-sorted packed col
    k_p2<<<NBUK, 256, 0, stream>>>(pairs, bbase, dinv, col);

    // 4. layer-1 gather (edge-parallel, weighted) -> bf16-packed h1b
    k_gather_ep<true><<<NBUK, 256, 0, stream>>>(hwb, col, bbase, dinv,
                                                scb, scb + 64, nullptr, h1b, nullptr);
    // 5. layer-2 GEMM (bf16 input; epilogue pre-scales rows by dinv)
    k_gemm2<<<GEMM1_B, 256, 0, stream>>>(h1b, W2, dinv, hwb);
    // 6. layer-2 gather (edge-parallel, unweighted, bf16 resid) -> f32 h
    k_gather_ep<false><<<NBUK, 256, 0, stream>>>(hwb, col, bbase, dinv,
                                                 scb + 128, scb + 192, h1b, nullptr, h);
    // 7. fused pooling + head
    k_poolhead<<<GG, 64, 0, stream>>>(h, gb, Wh1, bh1, Wh2, bh2, Wh3, bh3, out);
}

// Round 9
// 269.902 us; speedup vs baseline: 1.9186x; 1.9186x over previous
//
#include <hip/hip_runtime.h>
#include <math.h>

#define NN 100000
#define EE 1600000
#define GG 512
#define INF_ 128
#define HID 64
#define EPS 1e-5f

#define NBUK 391          // ceil(NN/256), bucket = dst >> 8
#define P1_TILES 98       // ceil((EE/4)/4096)
#define P1_PAD 104        // hblk row stride (98 padded to 8n for int4 loads)
#define GB_B 25           // graph-boundary role blocks
#define GEMM1_B 1563      // ceil(NN/64)

typedef unsigned int uint32;
typedef __attribute__((ext_vector_type(8))) short bf16x8;
typedef __attribute__((ext_vector_type(4))) float f32x4;
typedef __attribute__((ext_vector_type(2))) float f32x2;

// bf16 helpers: RNE pack, shift decode
static __device__ inline uint32 f2bf(float f) {
    uint32 u = __float_as_uint(f);
    return (u + 0x7FFFu + ((u >> 16) & 1u)) >> 16;
}
static __device__ inline float bf_lo(uint32 u) { return __uint_as_float(u << 16); }
static __device__ inline float bf_hi(uint32 u) { return __uint_as_float(u & 0xFFFF0000u); }

// History:
// R3: per-edge atomic scatter -> 12x cross-XCD write amp; bucketed 2-level sort.
// R9: single-histogram CSR build; 303us baseline.
// R10 FAILED: per-thread s[16] -> PromoteAlloca -> 64KB LDS, 38M bank conf.
// R11: gather memory-bound; instruction shaving (-30% VALU) bought only 5%.
// R12: launch fusion 10->8; 297.7. Gather at compulsory per-XCD L2-fill floor.
// R13: hwb fp8-e4m3 (table 6.4MB ~ L2-resident); 285.9. absmax 0 -> fp8 ok.
// R14 REGRESSED (299.8): 98-iter scalar-load loop in p1b (serialized latency).
// R15 (284.8): transposed hblk + int4 unrolled derivation fixed p1b.
// R16 (271.9): 2-node/wave interleaved gathers + bf16 h1. BEST VERIFIED.
// R17 FAILED (517.8): edge-parallel bucket gather. "Prefetch" rown depended
//      on un loaded in the SAME iteration -> serial 2-hop chain x256 edges
//      x391-block grid (1.5 blk/CU, 15% occ) = 158us/gather. Lesson: an
//      address prefetch is void if the address itself needs an in-loop load;
//      wave-per-node wins because all 16 index loads issue coalesced BEFORE
//      the row round. THIS FILE = exact R16 revert (verified 271.9).

// ---------------- shared GEMM body: [nrows,K]f32 @ W[K,64]f32 -> fp8 ------
// 64x64 tile/block, 4 waves x 4 n-tiles, 16x16x32 bf16 MFMA. Self-packs W.
// Rows padded +8 bf16: 256B-stride frag loads 16-way -> 2-way (free, m136).
// Epilogue: 4 cols packed per uint32 via v_cvt_pk_fp8_f32; optional dinv scale.
template <int K, bool SCALE>
__device__ __forceinline__ void gemm_body(const float* __restrict__ X,
        const float* __restrict__ W, const float* __restrict__ dinv,
        uint32* __restrict__ outb, int nrows, int bx,
        unsigned short* __restrict__ Al, unsigned short* __restrict__ Bl) {
    constexpr int KP = K + 8;
    int tid = threadIdx.x;
    // pack W transposed: Bl[n*KP + 2kp] = pack(W[2kp][n], W[2kp+1][n]).
    for (int i = tid; i < 64 * (K / 2); i += 256) {
        int n = i & 63, kp = i >> 6;
        uint32 lo = f2bf(W[(size_t)(2 * kp) * 64 + n]);
        uint32 hi = f2bf(W[(size_t)(2 * kp + 1) * 64 + n]);
        *(uint32*)&Bl[n * KP + kp * 2] = lo | (hi << 16);
    }
    int r0 = bx * 64;
    const float* Xb = X + (size_t)r0 * K;
    int limit = (nrows - r0) * K;
    for (int f = tid * 4; f < 64 * K; f += 1024) {
        float4 v = {0.f, 0.f, 0.f, 0.f};
        if (f + 3 < limit) v = *(const float4*)&Xb[f];
        int row = f / K, kpos = f % K;
        ushort4 pk;
        pk.x = (unsigned short)f2bf(v.x);
        pk.y = (unsigned short)f2bf(v.y);
        pk.z = (unsigned short)f2bf(v.z);
        pk.w = (unsigned short)f2bf(v.w);
        *(ushort4*)&Al[row * KP + kpos] = pk;
    }
    __syncthreads();
    int lane = tid & 63, wv = tid >> 6;
    int m = lane & 15, quad = lane >> 4;
    f32x4 acc0 = {0.f, 0.f, 0.f, 0.f}, acc1 = acc0, acc2 = acc0, acc3 = acc0;
    int arow = wv * 16 + m;
#pragma unroll
    for (int k0 = 0; k0 < K; k0 += 32) {
        int koff = k0 + quad * 8;
        bf16x8 a = *(const bf16x8*)&Al[arow * KP + koff];
        bf16x8 b0 = *(const bf16x8*)&Bl[(0 * 16 + m) * KP + koff];
        bf16x8 b1 = *(const bf16x8*)&Bl[(1 * 16 + m) * KP + koff];
        bf16x8 b2 = *(const bf16x8*)&Bl[(2 * 16 + m) * KP + koff];
        bf16x8 b3 = *(const bf16x8*)&Bl[(3 * 16 + m) * KP + koff];
        acc0 = __builtin_amdgcn_mfma_f32_16x16x32_bf16(a, b0, acc0, 0, 0, 0);
        acc1 = __builtin_amdgcn_mfma_f32_16x16x32_bf16(a, b1, acc1, 0, 0, 0);
        acc2 = __builtin_amdgcn_mfma_f32_16x16x32_bf16(a, b2, acc2, 0, 0, 0);
        acc3 = __builtin_amdgcn_mfma_f32_16x16x32_bf16(a, b3, acc3, 0, 0, 0);
    }
    // C/D layout: col = nt*16 + m, row = quad*4 + reg.
    float dv[4];
#pragma unroll
    for (int reg = 0; reg < 4; ++reg) {
        int row = r0 + wv * 16 + quad * 4 + reg;
        if (SCALE) dv[reg] = (row < nrows) ? dinv[row] : 0.f;
        else       dv[reg] = 1.f;
    }
    const float* accs[4] = {(const float*)&acc0, (const float*)&acc1,
                            (const float*)&acc2, (const float*)&acc3};
#pragma unroll
    for (int nt = 0; nt < 4; ++nt) {
#pragma unroll
        for (int reg = 0; reg < 4; ++reg) {
            float val = accs[nt][reg] * dv[reg];
            float v1 = __shfl_down(val, 1);
            float v2 = __shfl_down(val, 2);
            float v3 = __shfl_down(val, 3);
            int row = r0 + wv * 16 + quad * 4 + reg;
            if (((m & 3) == 0) && row < nrows) {
                int u = __builtin_amdgcn_cvt_pk_fp8_f32(val, v1, 0, false);
                u = __builtin_amdgcn_cvt_pk_fp8_f32(v2, v3, u, true);
                outb[(size_t)row * 16 + nt * 4 + (m >> 2)] = (uint32)u;
            }
        }
    }
}

// ------- mega front-end: hist | graph-bounds | setup | gemm1 (unscaled) ----
// hist writes hblk TRANSPOSED (bucket-major [NBUK][P1_PAD]) so p1b can
// vector-load each bucket's 98 per-block counts contiguously.
__global__ __launch_bounds__(256) void k_mega(const int* __restrict__ ei,
        int* __restrict__ hblk, const int* __restrict__ bat, int* __restrict__ gb,
        const float* __restrict__ x, const float* __restrict__ W1,
        uint32* __restrict__ hwb,
        const float* b1, const float* g1, const float* be1,
        const float* rm1, const float* rv1,
        const float* b2, const float* g2, const float* be2,
        const float* rm2, const float* rv2, float* sc) {
    __shared__ alignas(16) char smem[64 * (INF_ + 8) * 2 * 2];
    int b = blockIdx.x, t = threadIdx.x;
    if (b < P1_TILES) {
        int* h = (int*)smem;
        for (int i = t; i < NBUK; i += 256) h[i] = 0;
        __syncthreads();
        const int4* dst4 = (const int4*)(ei + EE);
        int base4 = b * 4096;
        for (int j = 0; j < 16; ++j) {
            int i4 = base4 + j * 256 + t;
            if (i4 < EE / 4) {
                int4 d = dst4[i4];
                atomicAdd(&h[d.x >> 8], 1);
                atomicAdd(&h[d.y >> 8], 1);
                atomicAdd(&h[d.z >> 8], 1);
                atomicAdd(&h[d.w >> 8], 1);
            }
        }
        __syncthreads();
        for (int i = t; i < NBUK; i += 256) hblk[i * P1_PAD + b] = h[i];
    } else if (b < P1_TILES + GB_B) {
        // gb[g] = first node index with batch >= g (batch sorted). gb[GG]=NN.
        int gid = (b - P1_TILES) * 256 + t;
        for (int i = gid; i < NN; i += GB_B * 256) {
            int bi = bat[i];
            if (i == 0) {
                for (int g = 0; g <= bi; ++g) gb[g] = 0;
            } else {
                int bp = bat[i - 1];
                for (int g = bp + 1; g <= bi; ++g) gb[g] = i;
            }
            if (i == NN - 1)
                for (int g = bi + 1; g <= GG; ++g) gb[g] = NN;
        }
    } else if (b < P1_TILES + GB_B + 1) {
        // setup role: BN fold (t<64), hwb zero row (64..79), hblk pad zero
        if (t < 64) {
            int l = t;
            float s1 = g1[l] * rsqrtf(rv1[l] + EPS);
            sc[l]       = s1;
            sc[64 + l]  = (b1[l] - rm1[l]) * s1 + be1[l];
            float s2 = g2[l] * rsqrtf(rv2[l] + EPS);
            sc[128 + l] = s2;
            sc[192 + l] = (b2[l] - rm2[l]) * s2 + be2[l];
        } else if (t < 80) {
            hwb[(size_t)NN * 16 + (t - 64)] = 0u;
        }
        // pads [98..104) of every hblk row (re-poisoned each run)
        for (int i = t; i < NBUK * (P1_PAD - P1_TILES); i += 256) {
            int k = i / (P1_PAD - P1_TILES);
            int bb = P1_TILES + i % (P1_PAD - P1_TILES);
            hblk[k * P1_PAD + bb] = 0;
        }
    } else {
        int bx = b - P1_TILES - GB_B - 1;
        unsigned short* Al = (unsigned short*)smem;
        unsigned short* Bl = (unsigned short*)(smem + 64 * (INF_ + 8) * 2);
        gemm_body<INF_, false>(x, W1, nullptr, hwb, NN, bx, Al, Bl);
    }
}

// -------- p1b: per-block rbase derivation + bucket scatter, 512 thr -------
// Thread t (<391) owns bucket t: 26 unrolled int4 loads over the transposed
// hblk row give total + partial(<b) in one latency round. Register wave-scan
// gives bucket bases; t=391 naturally yields EE. Block 0 publishes
// bbase/offs[NN]. Then bucket scatter (8x512 int4).
__global__ __launch_bounds__(512) void k_p1b(const int* __restrict__ ei,
                                             const int* __restrict__ hblk,
                                             uint32* __restrict__ pairs,
                                             int* __restrict__ bbase,
                                             int* __restrict__ offs) {
    __shared__ int h[NBUK];
    __shared__ int wsum[8];
    int b = blockIdx.x, t = threadIdx.x;
    int part = 0, c = 0;
    if (t < NBUK) {
        const int4* row = (const int4*)(hblk + t * P1_PAD);
#pragma unroll
        for (int q = 0; q < P1_PAD / 4; ++q) {
            int4 v = row[q];
            c += v.x + v.y + v.z + v.w;
            part += ((4 * q + 0 < b) ? v.x : 0) + ((4 * q + 1 < b) ? v.y : 0)
                  + ((4 * q + 2 < b) ? v.z : 0) + ((4 * q + 3 < b) ? v.w : 0);
        }
    }
    int lane = t & 63, w = t >> 6;
    int v = c;
    for (int d = 1; d < 64; d <<= 1) { int n = __shfl_up(v, d); if (lane >= d) v += n; }
    if (lane == 63) wsum[w] = v;
    __syncthreads();
    int pre = 0;
    for (int q = 0; q < w; ++q) pre += wsum[q];
    int excl = pre + v - c;
    if (t < NBUK) h[t] = excl + part;
    if (b == 0) {
        if (t <= NBUK) bbase[t] = excl;   // t=391 -> EE
        if (t == 0) offs[NN] = EE;
    }
    __syncthreads();
    const int4* src4 = (const int4*)ei;
    const int4* dst4 = (const int4*)(ei + EE);
    int base4 = b * 4096;
    for (int j = 0; j < 8; ++j) {
        int i4 = base4 + j * 512 + t;
        if (i4 < EE / 4) {
            int4 d = dst4[i4];
            int4 s = src4[i4];
            int p0 = atomicAdd(&h[d.x >> 8], 1);
            pairs[p0] = ((uint32)s.x << 8) | (uint32)(d.x & 255);
            int p1 = atomicAdd(&h[d.y >> 8], 1);
            pairs[p1] = ((uint32)s.y << 8) | (uint32)(d.y & 255);
            int p2 = atomicAdd(&h[d.z >> 8], 1);
            pairs[p2] = ((uint32)s.z << 8) | (uint32)(d.z & 255);
            int p3 = atomicAdd(&h[d.w >> 8], 1);
            pairs[p3] = ((uint32)s.w << 8) | (uint32)(d.w & 255);
        }
    }
}

// per-bucket (256 nodes) CSR finalize in LDS: count, scan, scatter col
__global__ __launch_bounds__(256) void k_p2(const uint32* __restrict__ pairs,
                                            const int* __restrict__ bbase,
                                            int* __restrict__ offs, float* __restrict__ dinv,
                                            int* __restrict__ col) {
    int b = blockIdx.x, t = threadIdx.x;
    int nbase = b << 8;
    int ebase = bbase[b], eend = bbase[b + 1];
    int m = eend - ebase;
    __shared__ int cnt[256];
    __shared__ int wsum[4];
    cnt[t] = 0;
    __syncthreads();
    for (int i = t; i < m; i += 256)
        atomicAdd(&cnt[pairs[ebase + i] & 255u], 1);
    __syncthreads();
    int c = cnt[t];
    int lane = t & 63, w = t >> 6;
    int v = c;
    for (int d = 1; d < 64; d <<= 1) { int n = __shfl_up(v, d); if (lane >= d) v += n; }
    if (lane == 63) wsum[w] = v;
    __syncthreads();
    int pre = 0;
    for (int q = 0; q < w; ++q) pre += wsum[q];
    int excl = pre + v - c;
    int node = nbase + t;
    if (node < NN) {
        offs[node] = ebase + excl;
        dinv[node] = rsqrtf(1.f + (float)c);
    }
    __syncthreads();
    cnt[t] = excl;
    __syncthreads();
    for (int i = t; i < m; i += 256) {
        uint32 u = pairs[ebase + i];
        int loc = atomicAdd(&cnt[u & 255u], 1);
        col[ebase + loc] = (int)(u >> 8);
    }
}

// ---- gather layer 1: WEIGHTED (hwb unscaled fp8), 2 nodes per wave -------
// Lane = (quarter=lane>>4, fl=lane&15). Nodes A=2i, B=2i+1 interleaved:
// both col chunks + 8 row-loads in flight per j-round (2 indep chains).
// Branchless masking: sentinel row NN (zeroed) + w=0. Output: bf16-packed h1.
__global__ void k_gcn_gather_w(const uint32* __restrict__ hwb, const int* __restrict__ col,
                               const int* __restrict__ offs,
                               const float* __restrict__ dinv, const float* __restrict__ scale,
                               const float* __restrict__ shift,
                               uint32* __restrict__ out) {
    int nodeA = blockIdx.x * 8 + (threadIdx.x >> 6) * 2;
    if (nodeA >= NN) return;
    int nodeB = nodeA + 1;
    int hasB = nodeB < NN;
    int lane = threadIdx.x & 63;
    int quarter = lane >> 4;
    int fl = lane & 15;                 // features 4fl .. 4fl+3
    int eA0 = offs[nodeA], eA1 = offs[nodeA + 1];
    int eB1 = hasB ? offs[nodeB + 1] : eA1;
    int eB0 = eA1;                      // CSR contiguous; empty if !hasB
    float diA = dinv[nodeA];
    float diB = hasB ? dinv[nodeB] : 0.f;
    uint32 uselfA = hwb[(size_t)nodeA * 16 + fl];
    uint32 uselfB = hwb[(size_t)(hasB ? nodeB : NN) * 16 + fl];
    float aA0 = 0.f, aA1 = 0.f, aA2 = 0.f, aA3 = 0.f;
    float aB0 = 0.f, aB1 = 0.f, aB2 = 0.f, aB3 = 0.f;
    int baseA = eA0, baseB = eB0;
    while (baseA < eA1 || baseB < eB1) {
        int mA = eA1 - baseA; mA = mA < 0 ? 0 : (mA > 64 ? 64 : mA);
        int mB = eB1 - baseB; mB = mB < 0 ? 0 : (mB > 64 ? 64 : mB);
        int sA = NN; float wA = 0.f;
        if (lane < mA) { sA = col[baseA + lane]; wA = dinv[sA]; }
        int sB = NN; float wB = 0.f;
        if (lane < mB) { sB = col[baseB + lane]; wB = dinv[sB]; }
        int mm = mA > mB ? mA : mB;
        for (int j = 0; j < mm; j += 16) {
            int   sa0 = __shfl(sA, j + quarter);
            int   sa1 = __shfl(sA, j + 4 + quarter);
            int   sa2 = __shfl(sA, j + 8 + quarter);
            int   sa3 = __shfl(sA, j + 12 + quarter);
            int   sb0 = __shfl(sB, j + quarter);
            int   sb1 = __shfl(sB, j + 4 + quarter);
            int   sb2 = __shfl(sB, j + 8 + quarter);
            int   sb3 = __shfl(sB, j + 12 + quarter);
            float wa0 = __shfl(wA, j + quarter);
            float wa1 = __shfl(wA, j + 4 + quarter);
            float wa2 = __shfl(wA, j + 8 + quarter);
            float wa3 = __shfl(wA, j + 12 + quarter);
            float wb0 = __shfl(wB, j + quarter);
            float wb1 = __shfl(wB, j + 4 + quarter);
            float wb2 = __shfl(wB, j + 8 + quarter);
            float wb3 = __shfl(wB, j + 12 + quarter);
            uint32 ua0 = hwb[(size_t)sa0 * 16 + fl];
            uint32 ua1 = hwb[(size_t)sa1 * 16 + fl];
            uint32 ua2 = hwb[(size_t)sa2 * 16 + fl];
            uint32 ua3 = hwb[(size_t)sa3 * 16 + fl];
            uint32 ub0 = hwb[(size_t)sb0 * 16 + fl];
            uint32 ub1 = hwb[(size_t)sb1 * 16 + fl];
            uint32 ub2 = hwb[(size_t)sb2 * 16 + fl];
            uint32 ub3 = hwb[(size_t)sb3 * 16 + fl];
            f32x2 la0 = __builtin_amdgcn_cvt_pk_f32_fp8((int)ua0, false);
            f32x2 ha0 = __builtin_amdgcn_cvt_pk_f32_fp8((int)ua0, true);
            f32x2 la1 = __builtin_amdgcn_cvt_pk_f32_fp8((int)ua1, false);
            f32x2 ha1 = __builtin_amdgcn_cvt_pk_f32_fp8((int)ua1, true);
            f32x2 la2 = __builtin_amdgcn_cvt_pk_f32_fp8((int)ua2, false);
            f32x2 ha2 = __builtin_amdgcn_cvt_pk_f32_fp8((int)ua2, true);
            f32x2 la3 = __builtin_amdgcn_cvt_pk_f32_fp8((int)ua3, false);
            f32x2 ha3 = __builtin_amdgcn_cvt_pk_f32_fp8((int)ua3, true);
            f32x2 lb0 = __builtin_amdgcn_cvt_pk_f32_fp8((int)ub0, false);
            f32x2 hb0 = __builtin_amdgcn_cvt_pk_f32_fp8((int)ub0, true);
            f32x2 lb1 = __builtin_amdgcn_cvt_pk_f32_fp8((int)ub1, false);
            f32x2 hb1 = __builtin_amdgcn_cvt_pk_f32_fp8((int)ub1, true);
            f32x2 lb2 = __builtin_amdgcn_cvt_pk_f32_fp8((int)ub2, false);
            f32x2 hb2 = __builtin_amdgcn_cvt_pk_f32_fp8((int)ub2, true);
            f32x2 lb3 = __builtin_amdgcn_cvt_pk_f32_fp8((int)ub3, false);
            f32x2 hb3 = __builtin_amdgcn_cvt_pk_f32_fp8((int)ub3, true);
            aA0 = fmaf(la0[0], wa0, aA0); aA1 = fmaf(la0[1], wa0, aA1);
            aA2 = fmaf(ha0[0], wa0, aA2); aA3 = fmaf(ha0[1], wa0, aA3);
            aB0 = fmaf(lb0[0], wb0, aB0); aB1 = fmaf(lb0[1], wb0, aB1);
            aB2 = fmaf(hb0[0], wb0, aB2); aB3 = fmaf(hb0[1], wb0, aB3);
            aA0 = fmaf(la1[0], wa1, aA0); aA1 = fmaf(la1[1], wa1, aA1);
            aA2 = fmaf(ha1[0], wa1, aA2); aA3 = fmaf(ha1[1], wa1, aA3);
            aB0 = fmaf(lb1[0], wb1, aB0); aB1 = fmaf(lb1[1], wb1, aB1);
            aB2 = fmaf(hb1[0], wb1, aB2); aB3 = fmaf(hb1[1], wb1, aB3);
            aA0 = fmaf(la2[0], wa2, aA0); aA1 = fmaf(la2[1], wa2, aA1);
            aA2 = fmaf(ha2[0], wa2, aA2); aA3 = fmaf(ha2[1], wa2, aA3);
            aB0 = fmaf(lb2[0], wb2, aB0); aB1 = fmaf(lb2[1], wb2, aB1);
            aB2 = fmaf(hb2[0], wb2, aB2); aB3 = fmaf(hb2[1], wb2, aB3);
            aA0 = fmaf(la3[0], wa3, aA0); aA1 = fmaf(la3[1], wa3, aA1);
            aA2 = fmaf(ha3[0], wa3, aA2); aA3 = fmaf(ha3[1], wa3, aA3);
            aB0 = fmaf(lb3[0], wb3, aB0); aB1 = fmaf(lb3[1], wb3, aB1);
            aB2 = fmaf(hb3[0], wb3, aB2); aB3 = fmaf(hb3[1], wb3, aB3);
        }
        baseA += 64; baseB += 64;
    }
    aA0 += __shfl_xor(aA0, 16); aA0 += __shfl_xor(aA0, 32);
    aA1 += __shfl_xor(aA1, 16); aA1 += __shfl_xor(aA1, 32);
    aA2 += __shfl_xor(aA2, 16); aA2 += __shfl_xor(aA2, 32);
    aA3 += __shfl_xor(aA3, 16); aA3 += __shfl_xor(aA3, 32);
    aB0 += __shfl_xor(aB0, 16); aB0 += __shfl_xor(aB0, 32);
    aB1 += __shfl_xor(aB1, 16); aB1 += __shfl_xor(aB1, 32);
    aB2 += __shfl_xor(aB2, 16); aB2 += __shfl_xor(aB2, 32);
    aB3 += __shfl_xor(aB3, 16); aB3 += __shfl_xor(aB3, 32);
    if (quarter == 0) {
        float4 sc4 = *(const float4*)&scale[4 * fl];
        float4 sh4 = *(const float4*)&shift[4 * fl];
        f32x2 sloA = __builtin_amdgcn_cvt_pk_f32_fp8((int)uselfA, false);
        f32x2 shiA = __builtin_amdgcn_cvt_pk_f32_fp8((int)uselfA, true);
        float diiA = diA * diA;
        float v0 = fmaf(aA0 * diA + sloA[0] * diiA, sc4.x, sh4.x);
        float v1 = fmaf(aA1 * diA + sloA[1] * diiA, sc4.y, sh4.y);
        float v2 = fmaf(aA2 * diA + shiA[0] * diiA, sc4.z, sh4.z);
        float v3 = fmaf(aA3 * diA + shiA[1] * diiA, sc4.w, sh4.w);
        v0 = fmaxf(v0, 0.f); v1 = fmaxf(v1, 0.f);
        v2 = fmaxf(v2, 0.f); v3 = fmaxf(v3, 0.f);
        uint2 oA;
        oA.x = f2bf(v0) | (f2bf(v1) << 16);
        oA.y = f2bf(v2) | (f2bf(v3) << 16);
        *(uint2*)&out[(size_t)nodeA * 32 + 2 * fl] = oA;
        if (hasB) {
            f32x2 sloB = __builtin_amdgcn_cvt_pk_f32_fp8((int)uselfB, false);
            f32x2 shiB = __builtin_amdgcn_cvt_pk_f32_fp8((int)uselfB, true);
            float diiB = diB * diB;
            float w0 = fmaf(aB0 * diB + sloB[0] * diiB, sc4.x, sh4.x);
            float w1 = fmaf(aB1 * diB + sloB[1] * diiB, sc4.y, sh4.y);
            float w2 = fmaf(aB2 * diB + shiB[0] * diiB, sc4.z, sh4.z);
            float w3 = fmaf(aB3 * diB + shiB[1] * diiB, sc4.w, sh4.w);
            w0 = fmaxf(w0, 0.f); w1 = fmaxf(w1, 0.f);
            w2 = fmaxf(w2, 0.f); w3 = fmaxf(w3, 0.f);
            uint2 oB;
            oB.x = f2bf(w0) | (f2bf(w1) << 16);
            oB.y = f2bf(w2) | (f2bf(w3) << 16);
            *(uint2*)&out[(size_t)nodeB * 32 + 2 * fl] = oB;
        }
    }
}

// ---- gather layer 2: UNWEIGHTED (hwb pre-scaled fp8), 2 nodes/wave,
//      bf16 resid, f32 out ------------------------------------------------
__global__ void k_gcn_gather(const uint32* __restrict__ hwb, const int* __restrict__ col,
                             const int* __restrict__ offs,
                             const float* __restrict__ dinv, const float* __restrict__ scale,
                             const float* __restrict__ shift, const uint32* __restrict__ resid,
                             float* __restrict__ out) {
    int nodeA = blockIdx.x * 8 + (threadIdx.x >> 6) * 2;
    if (nodeA >= NN) return;
    int nodeB = nodeA + 1;
    int hasB = nodeB < NN;
    int lane = threadIdx.x & 63;
    int quarter = lane >> 4;
    int fl = lane & 15;                 // features 4fl .. 4fl+3
    int eA0 = offs[nodeA], eA1 = offs[nodeA + 1];
    int eB1 = hasB ? offs[nodeB + 1] : eA1;
    int eB0 = eA1;
    float diA = dinv[nodeA];
    float diB = hasB ? dinv[nodeB] : 0.f;
    uint32 uselfA = hwb[(size_t)nodeA * 16 + fl];
    uint32 uselfB = hwb[(size_t)(hasB ? nodeB : NN) * 16 + fl];
    float aA0 = 0.f, aA1 = 0.f, aA2 = 0.f, aA3 = 0.f;
    float aB0 = 0.f, aB1 = 0.f, aB2 = 0.f, aB3 = 0.f;
    int baseA = eA0, baseB = eB0;
    while (baseA < eA1 || baseB < eB1) {
        int mA = eA1 - baseA; mA = mA < 0 ? 0 : (mA > 64 ? 64 : mA);
        int mB = eB1 - baseB; mB = mB < 0 ? 0 : (mB > 64 ? 64 : mB);
        int sA = NN;
        if (lane < mA) sA = col[baseA + lane];
        int sB = NN;
        if (lane < mB) sB = col[baseB + lane];
        int mm = mA > mB ? mA : mB;
        for (int j = 0; j < mm; j += 16) {
            int sa0 = __shfl(sA, j + quarter);
            int sa1 = __shfl(sA, j + 4 + quarter);
            int sa2 = __shfl(sA, j + 8 + quarter);
            int sa3 = __shfl(sA, j + 12 + quarter);
            int sb0 = __shfl(sB, j + quarter);
            int sb1 = __shfl(sB, j + 4 + quarter);
            int sb2 = __shfl(sB, j + 8 + quarter);
            int sb3 = __shfl(sB, j + 12 + quarter);
            uint32 ua0 = hwb[(size_t)sa0 * 16 + fl];
            uint32 ua1 = hwb[(size_t)sa1 * 16 + fl];
            uint32 ua2 = hwb[(size_t)sa2 * 16 + fl];
            uint32 ua3 = hwb[(size_t)sa3 * 16 + fl];
            uint32 ub0 = hwb[(size_t)sb0 * 16 + fl];
            uint32 ub1 = hwb[(size_t)sb1 * 16 + fl];
            uint32 ub2 = hwb[(size_t)sb2 * 16 + fl];
            uint32 ub3 = hwb[(size_t)sb3 * 16 + fl];
            f32x2 la0 = __builtin_amdgcn_cvt_pk_f32_fp8((int)ua0, false);
            f32x2 ha0 = __builtin_amdgcn_cvt_pk_f32_fp8((int)ua0, true);
            f32x2 la1 = __builtin_amdgcn_cvt_pk_f32_fp8((int)ua1, false);
            f32x2 ha1 = __builtin_amdgcn_cvt_pk_f32_fp8((int)ua1, true);
            f32x2 la2 = __builtin_amdgcn_cvt_pk_f32_fp8((int)ua2, false);
            f32x2 ha2 = __builtin_amdgcn_cvt_pk_f32_fp8((int)ua2, true);
            f32x2 la3 = __builtin_amdgcn_cvt_pk_f32_fp8((int)ua3, false);
            f32x2 ha3 = __builtin_amdgcn_cvt_pk_f32_fp8((int)ua3, true);
            f32x2 lb0 = __builtin_amdgcn_cvt_pk_f32_fp8((int)ub0, false);
            f32x2 hb0 = __builtin_amdgcn_cvt_pk_f32_fp8((int)ub0, true);
            f32x2 lb1 = __builtin_amdgcn_cvt_pk_f32_fp8((int)ub1, false);
            f32x2 hb1 = __builtin_amdgcn_cvt_pk_f32_fp8((int)ub1, true);
            f32x2 lb2 = __builtin_amdgcn_cvt_pk_f32_fp8((int)ub2, false);
            f32x2 hb2 = __builtin_amdgcn_cvt_pk_f32_fp8((int)ub2, true);
            f32x2 lb3 = __builtin_amdgcn_cvt_pk_f32_fp8((int)ub3, false);
            f32x2 hb3 = __builtin_amdgcn_cvt_pk_f32_fp8((int)ub3, true);
            aA0 += la0[0]; aA1 += la0[1]; aA2 += ha0[0]; aA3 += ha0[1];
            aB0 += lb0[0]; aB1 += lb0[1]; aB2 += hb0[0]; aB3 += hb0[1];
            aA0 += la1[0]; aA1 += la1[1]; aA2 += ha1[0]; aA3 += ha1[1];
            aB0 += lb1[0]; aB1 += lb1[1]; aB2 += hb1[0]; aB3 += hb1[1];
            aA0 += la2[0]; aA1 += la2[1]; aA2 += ha2[0]; aA3 += ha2[1];
            aB0 += lb2[0]; aB1 += lb2[1]; aB2 += hb2[0]; aB3 += hb2[1];
            aA0 += la3[0]; aA1 += la3[1]; aA2 += ha3[0]; aA3 += ha3[1];
            aB0 += lb3[0]; aB1 += lb3[1]; aB2 += hb3[0]; aB3 += hb3[1];
        }
        baseA += 64; baseB += 64;
    }
    aA0 += __shfl_xor(aA0, 16); aA0 += __shfl_xor(aA0, 32);
    aA1 += __shfl_xor(aA1, 16); aA1 += __shfl_xor(aA1, 32);
    aA2 += __shfl_xor(aA2, 16); aA2 += __shfl_xor(aA2, 32);
    aA3 += __shfl_xor(aA3, 16); aA3 += __shfl_xor(aA3, 32);
    aB0 += __shfl_xor(aB0, 16); aB0 += __shfl_xor(aB0, 32);
    aB1 += __shfl_xor(aB1, 16); aB1 += __shfl_xor(aB1, 32);
    aB2 += __shfl_xor(aB2, 16); aB2 += __shfl_xor(aB2, 32);
    aB3 += __shfl_xor(aB3, 16); aB3 += __shfl_xor(aB3, 32);
    if (quarter == 0) {
        float4 sc4 = *(const float4*)&scale[4 * fl];
        float4 sh4 = *(const float4*)&shift[4 * fl];
        f32x2 sloA = __builtin_amdgcn_cvt_pk_f32_fp8((int)uselfA, false);
        f32x2 shiA = __builtin_amdgcn_cvt_pk_f32_fp8((int)uselfA, true);
        float v0 = fmaf((aA0 + sloA[0]) * diA, sc4.x, sh4.x);
        float v1 = fmaf((aA1 + sloA[1]) * diA, sc4.y, sh4.y);
        float v2 = fmaf((aA2 + shiA[0]) * diA, sc4.z, sh4.z);
        float v3 = fmaf((aA3 + shiA[1]) * diA, sc4.w, sh4.w);
        uint2 rvA = *(const uint2*)&resid[(size_t)nodeA * 32 + 2 * fl];
        float4 oA;
        oA.x = fmaxf(v0, 0.f) + bf_lo(rvA.x);
        oA.y = fmaxf(v1, 0.f) + bf_hi(rvA.x);
        oA.z = fmaxf(v2, 0.f) + bf_lo(rvA.y);
        oA.w = fmaxf(v3, 0.f) + bf_hi(rvA.y);
        *(float4*)&out[(size_t)nodeA * 64 + 4 * fl] = oA;
        if (hasB) {
            f32x2 sloB = __builtin_amdgcn_cvt_pk_f32_fp8((int)uselfB, false);
            f32x2 shiB = __builtin_amdgcn_cvt_pk_f32_fp8((int)uselfB, true);
            float w0 = fmaf((aB0 + sloB[0]) * diB, sc4.x, sh4.x);
            float w1 = fmaf((aB1 + sloB[1]) * diB, sc4.y, sh4.y);
            float w2 = fmaf((aB2 + shiB[0]) * diB, sc4.z, sh4.z);
            float w3 = fmaf((aB3 + shiB[1]) * diB, sc4.w, sh4.w);
            uint2 rvB = *(const uint2*)&resid[(size_t)nodeB * 32 + 2 * fl];
            float4 oB;
            oB.x = fmaxf(w0, 0.f) + bf_lo(rvB.x);
            oB.y = fmaxf(w1, 0.f) + bf_hi(rvB.x);
            oB.z = fmaxf(w2, 0.f) + bf_lo(rvB.y);
            oB.w = fmaxf(w3, 0.f) + bf_hi(rvB.y);
            *(float4*)&out[(size_t)nodeB * 64 + 4 * fl] = oB;
        }
    }
}

// ---------------- fused pooling + MLP head: one block per graph -----------
__global__ void k_poolhead(const float* __restrict__ h, const int* __restrict__ gb,
                           const float* __restrict__ Wh1, const float* __restrict__ bh1,
                           const float* __restrict__ Wh2, const float* __restrict__ bh2,
                           const float* __restrict__ Wh3, const float* __restrict__ bh3,
                           float* __restrict__ out) {
    int g = blockIdx.x, t = threadIdx.x;  // 64 threads
    int lo = gb[g], hi = gb[g + 1];
    float s0 = 0.f, s1 = 0.f, s2 = 0.f, s3 = 0.f;
    float s4 = 0.f, s5 = 0.f, s6 = 0.f, s7 = 0.f;
    float m0 = 0.f, m1 = 0.f, m2 = 0.f, m3 = 0.f;
    float m4 = 0.f, m5 = 0.f, m6 = 0.f, m7 = 0.f;   // h >= 0 (post-ReLU chain)
    int i = lo;
    for (; i + 8 <= hi; i += 8) {
        float v0 = h[(size_t)(i + 0) * 64 + t];
        float v1 = h[(size_t)(i + 1) * 64 + t];
        float v2 = h[(size_t)(i + 2) * 64 + t];
        float v3 = h[(size_t)(i + 3) * 64 + t];
        float v4 = h[(size_t)(i + 4) * 64 + t];
        float v5 = h[(size_t)(i + 5) * 64 + t];
        float v6 = h[(size_t)(i + 6) * 64 + t];
        float v7 = h[(size_t)(i + 7) * 64 + t];
        s0 += v0; m0 = fmaxf(m0, v0);
        s1 += v1; m1 = fmaxf(m1, v1);
        s2 += v2; m2 = fmaxf(m2, v2);
        s3 += v3; m3 = fmaxf(m3, v3);
        s4 += v4; m4 = fmaxf(m4, v4);
        s5 += v5; m5 = fmaxf(m5, v5);
        s6 += v6; m6 = fmaxf(m6, v6);
        s7 += v7; m7 = fmaxf(m7, v7);
    }
    for (; i < hi; ++i) {
        float v = h[(size_t)i * 64 + t];
        s0 += v; m0 = fmaxf(m0, v);
    }
    float sum = ((s0 + s1) + (s2 + s3)) + ((s4 + s5) + (s6 + s7));
    float mx = fmaxf(fmaxf(fmaxf(m0, m1), fmaxf(m2, m3)),
                     fmaxf(fmaxf(m4, m5), fmaxf(m6, m7)));
    float c = fmaxf((float)(hi - lo), 1.f);
    __shared__ float hg[128];
    __shared__ float z1[64];
    __shared__ float z2[32];
    hg[t]      = sum / c;
    hg[64 + t] = mx;
    __syncthreads();
    float acc = bh1[t];
#pragma unroll 8
    for (int k = 0; k < 128; ++k) acc = fmaf(hg[k], Wh1[k * 64 + t], acc);
    z1[t] = fmaxf(acc, 0.f);
    __syncthreads();
    if (t < 32) {
        float a2 = bh2[t];
#pragma unroll 8
        for (int k = 0; k < 64; ++k) a2 = fmaf(z1[k], Wh2[k * 32 + t], a2);
        z2[t] = fmaxf(a2, 0.f);
    }
    __syncthreads();
    if (t == 0) {
        float a3 = bh3[0];
        for (int k = 0; k < 32; ++k) a3 = fmaf(z2[k], Wh3[k], a3);
        out[g] = 1.f / (1.f + expf(-a3));
    }
}

// ------- GEMM layer 2: bf16-packed input, dinv-scaled fp8 output ----------
// A-staging is a straight uint4 copy (input already bf16) -> no cvt work.
__global__ __launch_bounds__(256) void k_gemm2(const uint32* __restrict__ Xb16,
                                               const float* __restrict__ W,
                                               const float* __restrict__ dinv,
                                               uint32* __restrict__ outb) {
    constexpr int K = HID, KP = K + 8;
    __shared__ alignas(16) unsigned short Al[64 * KP];
    __shared__ alignas(16) unsigned short Bl[64 * KP];
    int tid = threadIdx.x;
    for (int i = tid; i < 64 * (K / 2); i += 256) {
        int n = i & 63, kp = i >> 6;
        uint32 lo = f2bf(W[(size_t)(2 * kp) * 64 + n]);
        uint32 hi = f2bf(W[(size_t)(2 * kp + 1) * 64 + n]);
        *(uint32*)&Bl[n * KP + kp * 2] = lo | (hi << 16);
    }
    int r0 = blockIdx.x * 64;
    const uint32* Xr = Xb16 + (size_t)r0 * 32;
    int limit = (NN - r0) * 32;           // u32 units
    for (int f = tid * 4; f < 64 * 32; f += 1024) {
        uint4 v = {0u, 0u, 0u, 0u};
        if (f + 3 < limit) v = *(const uint4*)&Xr[f];
        int row = f >> 5, kpos = (f & 31) * 2;  // bf16 elements
        *(uint4*)&Al[row * KP + kpos] = v;      // (row*72+kpos)*2 is 16B-aligned
    }
    __syncthreads();
    int lane = tid & 63, wv = tid >> 6;
    int m = lane & 15, quad = lane >> 4;
    f32x4 acc0 = {0.f, 0.f, 0.f, 0.f}, acc1 = acc0, acc2 = acc0, acc3 = acc0;
    int arow = wv * 16 + m;
#pragma unroll
    for (int k0 = 0; k0 < K; k0 += 32) {
        int koff = k0 + quad * 8;
        bf16x8 a = *(const bf16x8*)&Al[arow * KP + koff];
        bf16x8 b0 = *(const bf16x8*)&Bl[(0 * 16 + m) * KP + koff];
        bf16x8 b1 = *(const bf16x8*)&Bl[(1 * 16 + m) * KP + koff];
        bf16x8 b2 = *(const bf16x8*)&Bl[(2 * 16 + m) * KP + koff];
        bf16x8 b3 = *(const bf16x8*)&Bl[(3 * 16 + m) * KP + koff];
        acc0 = __builtin_amdgcn_mfma_f32_16x16x32_bf16(a, b0, acc0, 0, 0, 0);
        acc1 = __builtin_amdgcn_mfma_f32_16x16x32_bf16(a, b1, acc1, 0, 0, 0);
        acc2 = __builtin_amdgcn_mfma_f32_16x16x32_bf16(a, b2, acc2, 0, 0, 0);
        acc3 = __builtin_amdgcn_mfma_f32_16x16x32_bf16(a, b3, acc3, 0, 0, 0);
    }
    float dv[4];
#pragma unroll
    for (int reg = 0; reg < 4; ++reg) {
        int row = r0 + wv * 16 + quad * 4 + reg;
        dv[reg] = (row < NN) ? dinv[row] : 0.f;
    }
    const float* accs[4] = {(const float*)&acc0, (const float*)&acc1,
                            (const float*)&acc2, (const float*)&acc3};
#pragma unroll
    for (int nt = 0; nt < 4; ++nt) {
#pragma unroll
        for (int reg = 0; reg < 4; ++reg) {
            float val = accs[nt][reg] * dv[reg];
            float v1 = __shfl_down(val, 1);
            float v2 = __shfl_down(val, 2);
            float v3 = __shfl_down(val, 3);
            int row = r0 + wv * 16 + quad * 4 + reg;
            if (((m & 3) == 0) && row < NN) {
                int u = __builtin_amdgcn_cvt_pk_fp8_f32(val, v1, 0, false);
                u = __builtin_amdgcn_cvt_pk_fp8_f32(v2, v3, u, true);
                outb[(size_t)row * 16 + nt * 4 + (m >> 2)] = (uint32)u;
            }
        }
    }
}

// ---------------- launcher ----------------

static inline size_t alignup(size_t x) { return (x + 255) & ~(size_t)255; }

extern "C" void kernel_launch(void* const* d_in, const int* in_sizes, int n_in,
                              void* d_out, int out_size, void* d_ws, size_t ws_size,
                              hipStream_t stream) {
    const float* x   = (const float*)d_in[0];
    const int*   ei  = (const int*)d_in[1];
    const int*   bat = (const int*)d_in[2];
    const float* W1  = (const float*)d_in[3];
    const float* b1  = (const float*)d_in[4];
    const float* g1  = (const float*)d_in[5];
    const float* be1 = (const float*)d_in[6];
    const float* rm1 = (const float*)d_in[7];
    const float* rv1 = (const float*)d_in[8];
    const float* W2  = (const float*)d_in[9];
    const float* b2  = (const float*)d_in[10];
    const float* g2  = (const float*)d_in[11];
    const float* be2 = (const float*)d_in[12];
    const float* rm2 = (const float*)d_in[13];
    const float* rv2 = (const float*)d_in[14];
    const float* Wh1 = (const float*)d_in[15];
    const float* bh1 = (const float*)d_in[16];
    const float* Wh2 = (const float*)d_in[17];
    const float* bh2 = (const float*)d_in[18];
    const float* Wh3 = (const float*)d_in[19];
    const float* bh3 = (const float*)d_in[20];
    float* out = (float*)d_out;

    char* ws = (char*)d_ws;
    size_t o = 0;
    int*   hblk   = (int*)(ws + o);  o = alignup(o + (size_t)NBUK * P1_PAD * 4);
    int*   bbase  = (int*)(ws + o);  o = alignup(o + (NBUK + 1) * 4);
    int*   offs   = (int*)(ws + o);  o = alignup(o + (NN + 1) * 4);
    uint32* pairs = (uint32*)(ws + o); o = alignup(o + (size_t)EE * 4);
    int*   col    = (int*)(ws + o);  o = alignup(o + (size_t)EE * 4);
    float* dinv   = (float*)(ws + o); o = alignup(o + (size_t)NN * 4);
    float* scb    = (float*)(ws + o); o = alignup(o + 4 * 64 * 4);
    int*   gb     = (int*)(ws + o);  o = alignup(o + (GG + 1) * 4);
    uint32* hwb   = (uint32*)(ws + o); o = alignup(o + (size_t)(NN + 1) * 16 * 4); // fp8 rows, +1 zero row
    uint32* h1b   = (uint32*)(ws + o); o = alignup(o + (size_t)NN * 32 * 4);       // bf16-packed layer-1 out
    float* h      = (float*)(ws + o); o = alignup(o + (size_t)NN * 64 * 4);
    (void)ws_size; (void)n_in; (void)in_sizes; (void)out_size;

    // 1. front-end: hist(transposed) || graph-bounds || setup || gemm1
    k_mega<<<P1_TILES + GB_B + 1 + GEMM1_B, 256, 0, stream>>>(
        ei, hblk, bat, gb, x, W1, hwb,
        b1, g1, be1, rm1, rv1, b2, g2, be2, rm2, rv2, scb);
    // 2. bucket scatter (vector-load rbase derivation; publishes bbase/offs[NN])
    k_p1b<<<P1_TILES, 512, 0, stream>>>(ei, hblk, pairs, bbase, offs);
    // 3. CSR finalize
    k_p2<<<NBUK, 256, 0, stream>>>(pairs, bbase, offs, dinv, col);

    // 4. layer-1 gather (weighted, 2 nodes/wave) -> bf16-packed h1b
    k_gcn_gather_w<<<(NN + 7) / 8, 256, 0, stream>>>(hwb, col, offs, dinv,
                                                     scb, scb + 64, h1b);
    // 5. layer-2 GEMM (bf16 input; epilogue pre-scales rows by dinv)
    k_gemm2<<<GEMM1_B, 256, 0, stream>>>(h1b, W2, dinv, hwb);
    // 6. layer-2 gather (unweighted, 2 nodes/wave, bf16 resid) -> f32 h
    k_gcn_gather<<<(NN + 7) / 8, 256, 0, stream>>>(hwb, col, offs, dinv,
                                                   scb + 128, scb + 192, h1b, h);
    // 7. fused pooling + head
    k_poolhead<<<GG, 64, 0, stream>>>(h, gb, Wh1, bh1, Wh2, bh2, Wh3, bh3, out);
}